// Round 5
// baseline (197.295 us; speedup 1.0000x reference)
//
#include <hip/hip_runtime.h>
#include <hip/hip_bf16.h>

#define BATCH    32768
#define HD       256
#define TM       32
#define NTHREADS 512

#define SCL    2.8853900817779268f   // 2*log2(e): tanh(x) = 1 - 2/(exp2(SCL*x)+1)
#define SCLINV 0.3465735902799726f   // 1/SCL

typedef short  short8  __attribute__((ext_vector_type(8)));
typedef float  f32x16  __attribute__((ext_vector_type(16)));

// scalar f32 -> bf16 RNE (prepack only)
__device__ __forceinline__ unsigned short f2bf(float f) {
    unsigned u = __float_as_uint(f);
    return (unsigned short)((u + 0x7FFFu + ((u >> 16) & 1u)) >> 16);
}

// packed f32 pair -> bf16x2 (v_cvt_pk_bf16_f32)
__device__ __forceinline__ unsigned pk2(float a, float b) {
    __hip_bfloat162 h = __float22bfloat162_rn(make_float2(a, b));
    return *reinterpret_cast<unsigned*>(&h);
}

// ---- prepack W2^T (scaled by SCL) into bf16 MFMA A-fragment order ----
// A-frag for v_mfma_f32_32x32x16_bf16: lane l holds A[mt*32 + (l&31)][kstep*16 + (l>>5)*8 + i]
// where A = SCL * W2^T. chunk (mt, kstep) at ((mt*16 + kstep)*64 + lane)*8 + i
__global__ void prepack_w2t(const float* __restrict__ W2, unsigned short* __restrict__ wsA) {
    const int k = blockIdx.x;        // K row of W2
    const int j = threadIdx.x;       // output column j (row of W2^T)
    const unsigned short b = f2bf(SCL * W2[k * HD + j]);
    const int kstep = k >> 4, kl = k & 15, hi2 = kl >> 3, i = kl & 7;
    const int mt = j >> 5, jl = j & 31;
    wsA[(((mt * 16) + kstep) * 64 + (hi2 * 32 + jl)) * 8 + i] = b;
}

__global__ __launch_bounds__(NTHREADS, 8)
void cnf1d_rk4_mfma4(const float* __restrict__ z0,
                     const float* __restrict__ W1,
                     const float* __restrict__ b1,
                     const float* __restrict__ b2,
                     const float* __restrict__ W3,
                     const float* __restrict__ b3,
                     const unsigned short* __restrict__ wsA,
                     float* __restrict__ out)
{
    // B staging: [h1^T cols 0..31 ; th1^T cols 32..63], bf16, blocked:
    // 16B slot (kgranule g = k/8, row) at uint4 index g*64 + row
    __shared__ __align__(16) short Abuf[64 * 256];    // 32 KB
    __shared__ float4 pt[HD];                         // (SCL*w1z, SCL*w1t, SCL*b1, w1z) 4 KB
    __shared__ float  b2sc[HD], w3t[HD];              // SCL*b2, W3   2 KB
    __shared__ float2 kz[8][TM];                      // per-wave (pdz,pdd) 2 KB
                                                      // total 40,960 B -> 4 blocks/CU
    const int tid  = threadIdx.x;
    const int s0   = blockIdx.x * TM;
    const int lane = tid & 63;
    const int ln31 = lane & 31;
    const int hi   = lane >> 5;
    const int wid  = tid >> 6;        // wave id 0..7: owns j in [wid*32, wid*32+32)
    const int s    = tid & 31;        // owned sample
    const int fb   = tid >> 5;        // phase-1 feature block 0..15 (16 features)

    if (tid < HD) {
        const float w0 = W1[tid];
        pt[tid]   = make_float4(SCL * w0, SCL * W1[HD + tid], SCL * b1[tid], w0);
        b2sc[tid] = SCL * b2[tid];
        w3t[tid]  = W3[tid];
    }
    float zbr = z0[s0 + s];
    float zcr = zbr, skzr = 0.f, skdr = 0.f, daccr = 0.f;
    __syncthreads();

    const float dt  = 0.25f;
    const float b3v = b3[0];
    const short8* __restrict__ wsA8 = (const short8*)wsA;
    uint4* __restrict__ Ab4 = (uint4*)Abuf;
    const short8* __restrict__ Ab8 = (const short8*)Abuf;
    const int jb = wid * 32 + hi * 4;

    for (int it = 0; it < 16; ++it) {
        const int e    = it & 3;
        const int step = it >> 2;
        const float te = step * dt + ((e == 0) ? 0.f : ((e == 3) ? dt : 0.5f * dt));

        // ---- phase 1: h1/th1 -> bf16 staging (16 features per thread) ----
        #pragma unroll
        for (int g2 = 0; g2 < 2; ++g2) {
            const int j0 = fb * 16 + g2 * 8;
            float h[8], th[8];
            #pragma unroll
            for (int ee = 0; ee < 8; ++ee) {
                const float4 p = pt[j0 + ee];
                const float a  = fmaf(zcr, p.x, fmaf(te, p.y, p.z));   // scaled pre-act
                const float ev = __builtin_amdgcn_exp2f(a);
                const float r1 = __builtin_amdgcn_rcpf(ev + 1.0f);
                const float hh = fmaf(-2.f, r1, 1.f);                  // tanh
                h[ee]  = hh;
                th[ee] = (1.f - hh * hh) * p.w;                        // dtanh * w1z
            }
            uint4 vU, vT;
            vU.x = pk2(h[0], h[1]);   vU.y = pk2(h[2], h[3]);
            vU.z = pk2(h[4], h[5]);   vU.w = pk2(h[6], h[7]);
            vT.x = pk2(th[0], th[1]); vT.y = pk2(th[2], th[3]);
            vT.z = pk2(th[4], th[5]); vT.w = pk2(th[6], th[7]);
            const int gr = j0 >> 3;
            Ab4[gr * 64 + s]      = vU;   // U col s
            Ab4[gr * 64 + 32 + s] = vT;   // T col 32+s
        }
        __syncthreads();

        // ---- phase 2: acc = SCL*(W2^T[j-tile] @ [h1;th1]^T) + SCL*b2 ----
        f32x16 accU, accT;
        #pragma unroll
        for (int rq = 0; rq < 4; ++rq) {
            const float4 bq = *(const float4*)&b2sc[jb + rq * 8];
            accU[rq * 4 + 0] = bq.x;  accU[rq * 4 + 1] = bq.y;
            accU[rq * 4 + 2] = bq.z;  accU[rq * 4 + 3] = bq.w;
            accT[rq * 4 + 0] = 0.f;   accT[rq * 4 + 1] = 0.f;
            accT[rq * 4 + 2] = 0.f;   accT[rq * 4 + 3] = 0.f;
        }

        #pragma unroll 4
        for (int kk = 0; kk < 16; ++kk) {
            const short8 hU = Ab8[(kk * 2 + hi) * 64 + ln31];
            const short8 hT = Ab8[(kk * 2 + hi) * 64 + 32 + ln31];
            const short8 aW = wsA8[(wid * 16 + kk) * 64 + lane];
            accU = __builtin_amdgcn_mfma_f32_32x32x16_bf16(aW, hU, accU, 0, 0, 0);
            accT = __builtin_amdgcn_mfma_f32_32x32x16_bf16(aW, hT, accT, 0, 0, 0);
        }

        // ---- phase 3: epilogue; j-reduction in-lane (lane = sample) ----
        float pdz = 0.f, pdd = 0.f;
        #pragma unroll
        for (int rq = 0; rq < 4; ++rq) {
            const float4 w3q = *(const float4*)&w3t[jb + rq * 8];
            #pragma unroll
            for (int rr = 0; rr < 4; ++rr) {
                const int r = rq * 4 + rr;
                const float ev  = __builtin_amdgcn_exp2f(accU[r]);     // acc = SCL*(u+b2)
                const float r1  = __builtin_amdgcn_rcpf(ev + 1.0f);
                const float h2  = fmaf(-2.f, r1, 1.f);
                const float tus = accT[r];                             // SCL*tu
                const float th2 = fmaf(-h2 * h2, tus, tus);            // (1-h2^2)*SCL*tu
                const float w3c = ((const float*)&w3q)[rr];
                pdz = fmaf(h2,  w3c, pdz);
                pdd = fmaf(th2, w3c, pdd);
            }
        }
        pdd *= SCLINV;                       // undo tangent scale once
        pdz += __shfl_xor(pdz, 32);          // combine hi halves (j += 4 rows)
        pdd += __shfl_xor(pdd, 32);
        if (hi == 0) kz[wid][ln31] = make_float2(pdz, pdd);
        __syncthreads();

        // ---- phase 4: RK4 update (registers, redundant across threads of a sample) ----
        {
            float k_z = b3v, k_d = 0.f;
            #pragma unroll
            for (int w = 0; w < 8; ++w) {
                const float2 a = kz[w][s];
                k_z += a.x; k_d += a.y;
            }
            const float cw = (e == 1 || e == 2) ? 2.f : 1.f;
            skzr += cw * k_z;
            skdr += cw * k_d;
            if (e < 3) {
                zcr = fmaf((e == 2) ? dt : 0.5f * dt, k_z, zbr);
            } else {
                zbr   = fmaf(dt / 6.f, skzr, zbr);
                zcr   = zbr;
                daccr = fmaf(dt / 6.f, skdr, daccr);
                skzr = 0.f; skdr = 0.f;
            }
        }
    }

    if (tid < TM) {
        out[s0 + tid]         = zbr;     // zf
        out[BATCH + s0 + tid] = daccr;   // div_int
    }
}

extern "C" void kernel_launch(void* const* d_in, const int* in_sizes, int n_in,
                              void* d_out, int out_size, void* d_ws, size_t ws_size,
                              hipStream_t stream) {
    const float* z0 = (const float*)d_in[0];
    const float* W1 = (const float*)d_in[1];
    const float* b1 = (const float*)d_in[2];
    const float* W2 = (const float*)d_in[3];
    const float* b2 = (const float*)d_in[4];
    const float* W3 = (const float*)d_in[5];
    const float* b3 = (const float*)d_in[6];
    float* out = (float*)d_out;
    unsigned short* wsA = (unsigned short*)d_ws;   // 128 KB bf16 A-frag W2^T (scaled)

    hipLaunchKernelGGL(prepack_w2t, dim3(HD), dim3(HD), 0, stream, W2, wsA);
    hipLaunchKernelGGL(cnf1d_rk4_mfma4, dim3(BATCH / TM), dim3(NTHREADS), 0, stream,
                       z0, W1, b1, b2, W3, b3, wsA, out);
}

// Round 6
// 164.145 us; speedup vs baseline: 1.2020x; 1.2020x over previous
//
#include <hip/hip_runtime.h>
#include <hip/hip_bf16.h>

#define BATCH    32768
#define HD       256
#define TM       32
#define NTHREADS 512

#define SCL    2.8853900817779268f   // 2*log2(e): tanh(x) = 1 - 2/(exp2(SCL*x)+1)
#define SCLINV 0.3465735902799726f   // 1/SCL

typedef short  short8  __attribute__((ext_vector_type(8)));
typedef float  f32x16  __attribute__((ext_vector_type(16)));

// scalar f32 -> bf16 RNE (prepack only)
__device__ __forceinline__ unsigned short f2bf(float f) {
    unsigned u = __float_as_uint(f);
    return (unsigned short)((u + 0x7FFFu + ((u >> 16) & 1u)) >> 16);
}

// packed f32 pair -> bf16x2 (v_cvt_pk_bf16_f32)
__device__ __forceinline__ unsigned pk2(float a, float b) {
    __hip_bfloat162 h = __float22bfloat162_rn(make_float2(a, b));
    return *reinterpret_cast<unsigned*>(&h);
}

// ---- prepack W2^T (scaled by SCL) into bf16 MFMA A-fragment order ----
// A-frag for v_mfma_f32_32x32x16_bf16: lane l holds A[mt*32 + (l&31)][kstep*16 + (l>>5)*8 + i]
// where A = SCL * W2^T. chunk (mt, kstep) at ((mt*16 + kstep)*64 + lane)*8 + i
__global__ void prepack_w2t(const float* __restrict__ W2, unsigned short* __restrict__ wsA) {
    const int k = blockIdx.x;        // K row of W2
    const int j = threadIdx.x;       // output column j (row of W2^T)
    const unsigned short b = f2bf(SCL * W2[k * HD + j]);
    const int kstep = k >> 4, kl = k & 15, hi2 = kl >> 3, i = kl & 7;
    const int mt = j >> 5, jl = j & 31;
    wsA[(((mt * 16) + kstep) * 64 + (hi2 * 32 + jl)) * 8 + i] = b;
}

__global__ __launch_bounds__(NTHREADS, 4)
void cnf1d_rk4_mfma5(const float* __restrict__ z0,
                     const float* __restrict__ W1,
                     const float* __restrict__ b1,
                     const float* __restrict__ b2,
                     const float* __restrict__ W3,
                     const float* __restrict__ b3,
                     const unsigned short* __restrict__ wsA,
                     float* __restrict__ out)
{
    // B staging: [h1^T cols 0..31 ; th1^T cols 32..63], bf16, blocked:
    // 16B slot (kgranule g = k/8, row) at uint4 index g*64 + row
    __shared__ __align__(16) short Abuf[64 * 256];    // 32 KB
    __shared__ float4 pt[HD];                         // (SCL*w1z, SCL*w1t, SCL*b1, w1z) 4 KB
    __shared__ float  b2sc[HD], w3t[HD];              // SCL*b2, W3   2 KB
    __shared__ float2 kz[8][TM];                      // per-wave (pdz,pdd) 2 KB
                                                      // total 40,960 B
    const int tid  = threadIdx.x;
    const int s0   = blockIdx.x * TM;
    const int lane = tid & 63;
    const int ln31 = lane & 31;
    const int hi   = lane >> 5;
    const int wid  = tid >> 6;        // wave id 0..7: owns j in [wid*32, wid*32+32)
    const int s    = tid & 31;        // owned sample
    const int fb   = tid >> 5;        // phase-1 feature block 0..15 (16 features)

    if (tid < HD) {
        const float w0 = W1[tid];
        pt[tid]   = make_float4(SCL * w0, SCL * W1[HD + tid], SCL * b1[tid], w0);
        b2sc[tid] = SCL * b2[tid];
        w3t[tid]  = W3[tid];
    }

    // ---- loop-invariant: this wave's W2^T fragments, held in registers (64 VGPR) ----
    const short8* __restrict__ wsA8 = (const short8*)wsA;
    short8 w2f[16];
    #pragma unroll
    for (int kk = 0; kk < 16; ++kk)
        w2f[kk] = wsA8[(wid * 16 + kk) * 64 + lane];

    float zbr = z0[s0 + s];
    float zcr = zbr, skzr = 0.f, skdr = 0.f, daccr = 0.f;
    __syncthreads();

    const float dt  = 0.25f;
    const float b3v = b3[0];
    uint4* __restrict__ Ab4 = (uint4*)Abuf;
    const short8* __restrict__ Ab8 = (const short8*)Abuf;
    const int jb = wid * 32 + hi * 4;

    for (int it = 0; it < 16; ++it) {
        const int e    = it & 3;
        const int step = it >> 2;
        const float te = step * dt + ((e == 0) ? 0.f : ((e == 3) ? dt : 0.5f * dt));

        // ---- phase 1: h1/th1 -> bf16 staging (16 features per thread) ----
        #pragma unroll
        for (int g2 = 0; g2 < 2; ++g2) {
            const int j0 = fb * 16 + g2 * 8;
            float h[8], th[8];
            #pragma unroll
            for (int ee = 0; ee < 8; ++ee) {
                const float4 p = pt[j0 + ee];
                const float a  = fmaf(zcr, p.x, fmaf(te, p.y, p.z));   // scaled pre-act
                const float ev = __builtin_amdgcn_exp2f(a);
                const float r1 = __builtin_amdgcn_rcpf(ev + 1.0f);
                const float hh = fmaf(-2.f, r1, 1.f);                  // tanh
                h[ee]  = hh;
                th[ee] = (1.f - hh * hh) * p.w;                        // dtanh * w1z
            }
            uint4 vU, vT;
            vU.x = pk2(h[0], h[1]);   vU.y = pk2(h[2], h[3]);
            vU.z = pk2(h[4], h[5]);   vU.w = pk2(h[6], h[7]);
            vT.x = pk2(th[0], th[1]); vT.y = pk2(th[2], th[3]);
            vT.z = pk2(th[4], th[5]); vT.w = pk2(th[6], th[7]);
            const int gr = j0 >> 3;
            Ab4[gr * 64 + s]      = vU;   // U col s
            Ab4[gr * 64 + 32 + s] = vT;   // T col 32+s
        }
        __syncthreads();

        // ---- phase 2: acc = SCL*(W2^T[j-tile] @ [h1;th1]^T) + SCL*b2 ----
        f32x16 accU, accT;
        #pragma unroll
        for (int rq = 0; rq < 4; ++rq) {
            const float4 bq = *(const float4*)&b2sc[jb + rq * 8];
            accU[rq * 4 + 0] = bq.x;  accU[rq * 4 + 1] = bq.y;
            accU[rq * 4 + 2] = bq.z;  accU[rq * 4 + 3] = bq.w;
            accT[rq * 4 + 0] = 0.f;   accT[rq * 4 + 1] = 0.f;
            accT[rq * 4 + 2] = 0.f;   accT[rq * 4 + 3] = 0.f;
        }

        #pragma unroll
        for (int kk = 0; kk < 16; ++kk) {
            const short8 hU = Ab8[(kk * 2 + hi) * 64 + ln31];
            const short8 hT = Ab8[(kk * 2 + hi) * 64 + 32 + ln31];
            accU = __builtin_amdgcn_mfma_f32_32x32x16_bf16(w2f[kk], hU, accU, 0, 0, 0);
            accT = __builtin_amdgcn_mfma_f32_32x32x16_bf16(w2f[kk], hT, accT, 0, 0, 0);
        }

        // ---- phase 3: epilogue; j-reduction in-lane (lane = sample) ----
        float pdz = 0.f, pdd = 0.f;
        #pragma unroll
        for (int rq = 0; rq < 4; ++rq) {
            const float4 w3q = *(const float4*)&w3t[jb + rq * 8];
            #pragma unroll
            for (int rr = 0; rr < 4; ++rr) {
                const int r = rq * 4 + rr;
                const float ev  = __builtin_amdgcn_exp2f(accU[r]);     // acc = SCL*(u+b2)
                const float r1  = __builtin_amdgcn_rcpf(ev + 1.0f);
                const float h2  = fmaf(-2.f, r1, 1.f);
                const float tus = accT[r];                             // SCL*tu
                const float th2 = fmaf(-h2 * h2, tus, tus);            // (1-h2^2)*SCL*tu
                const float w3c = ((const float*)&w3q)[rr];
                pdz = fmaf(h2,  w3c, pdz);
                pdd = fmaf(th2, w3c, pdd);
            }
        }
        pdd *= SCLINV;                       // undo tangent scale once
        pdz += __shfl_xor(pdz, 32);          // combine hi halves (j += 4 rows)
        pdd += __shfl_xor(pdd, 32);
        if (hi == 0) kz[wid][ln31] = make_float2(pdz, pdd);
        __syncthreads();

        // ---- phase 4: RK4 update (registers, redundant across threads of a sample) ----
        {
            float k_z = b3v, k_d = 0.f;
            #pragma unroll
            for (int w = 0; w < 8; ++w) {
                const float2 a = kz[w][s];
                k_z += a.x; k_d += a.y;
            }
            const float cw = (e == 1 || e == 2) ? 2.f : 1.f;
            skzr += cw * k_z;
            skdr += cw * k_d;
            if (e < 3) {
                zcr = fmaf((e == 2) ? dt : 0.5f * dt, k_z, zbr);
            } else {
                zbr   = fmaf(dt / 6.f, skzr, zbr);
                zcr   = zbr;
                daccr = fmaf(dt / 6.f, skdr, daccr);
                skzr = 0.f; skdr = 0.f;
            }
        }
    }

    if (tid < TM) {
        out[s0 + tid]         = zbr;     // zf
        out[BATCH + s0 + tid] = daccr;   // div_int
    }
}

extern "C" void kernel_launch(void* const* d_in, const int* in_sizes, int n_in,
                              void* d_out, int out_size, void* d_ws, size_t ws_size,
                              hipStream_t stream) {
    const float* z0 = (const float*)d_in[0];
    const float* W1 = (const float*)d_in[1];
    const float* b1 = (const float*)d_in[2];
    const float* W2 = (const float*)d_in[3];
    const float* b2 = (const float*)d_in[4];
    const float* W3 = (const float*)d_in[5];
    const float* b3 = (const float*)d_in[6];
    float* out = (float*)d_out;
    unsigned short* wsA = (unsigned short*)d_ws;   // 128 KB bf16 A-frag W2^T (scaled)

    hipLaunchKernelGGL(prepack_w2t, dim3(HD), dim3(HD), 0, stream, W2, wsA);
    hipLaunchKernelGGL(cnf1d_rk4_mfma5, dim3(BATCH / TM), dim3(NTHREADS), 0, stream,
                       z0, W1, b1, b2, W3, b3, wsA, out);
}